// Round 16
// baseline (53.033 us; speedup 1.0000x reference)
//
#include <hip/hip_runtime.h>

using u32 = unsigned int;

typedef __attribute__((ext_vector_type(8))) _Float16 f16x8;
typedef __attribute__((ext_vector_type(4))) float    f32x4;

// ---------------------------------------------------------------------------
// prep: WcatT[n][kk] = s(i,kb) * W[c][(i^kb)*256 + u]   (f16, 1024x1024)
// sign bits packed: bit (4*i + kb) of 0x3950
// ---------------------------------------------------------------------------
__global__ __launch_bounds__(256) void build_wcatT(const float* __restrict__ W,
                                                   _Float16* __restrict__ Wt) {
    int t  = blockIdx.x * 256 + threadIdx.x;
    int n  = t >> 10, kk = t & 1023;
    int kb = n >> 8,  u  = n & 255;
    int i  = kk >> 8, c  = kk & 255;
    int j  = i ^ kb;
    float v = W[c * 1024 + j * 256 + u];
    if ((0x3950u >> (i * 4 + kb)) & 1u) v = -v;
    Wt[t] = (_Float16)v;
}

// ---------------------------------------------------------------------------
// GEMM, 8-phase schedule + fused f32->f16 A-cast.  M=16384 N=1024 K=1024.
//   256x256 tile, BK=64 (16 K-tiles), kh0/kh1 K-halves.
//   LDS per dbuf (f16 offs): A-kh0 @0, A-kh1 @8192, B-kh0 @16384, B-kh1 @24576.
//   2 dbufs (stride 32768 f16) = 128 KiB. 8 waves (2M x 4N), acc[8][4].
//   R16 change vs R15: vmcnt gates thinned from 4/K-tile to 2/K-tile
//   (ph2 and ph4 only, m201 discipline); ph1/ph3 are pure
//   {ds_read || issue || MFMA} with no waits. Ledger (12 vmem/tile):
//   entering tile t queue = [A-k1(t):4, B-kh1(t):2];
//   ph2 VMW(6) drains exactly that group (v regs -> WRITE_A kh1; B-kh1 LDS);
//   ph4 VMW(6) drains [A-k0(t+1):4, B-kh0(t+1):2] (u -> WRITE_A kh0 next).
//   All issue->drain distances >= 2 phases. Never vmcnt(0) in steady state.
//   Swizzle both sides: phys_chunk = c ^ ((row>>1)&3)  (0-conflict, measured).
// ---------------------------------------------------------------------------
__device__ __forceinline__ void async16(const void* g, void* l) {
    __builtin_amdgcn_global_load_lds((const __attribute__((address_space(1))) u32*)g,
                                     (__attribute__((address_space(3))) u32*)l,
                                     16, 0, 0);
}

#define BARRIER() do { asm volatile("" ::: "memory"); \
                       __builtin_amdgcn_s_barrier(); \
                       asm volatile("" ::: "memory"); } while (0)

#define VMW(n)  asm volatile("s_waitcnt vmcnt(" #n ")" ::: "memory")
#define LGKM0() asm volatile("s_waitcnt lgkmcnt(0)" ::: "memory")
#define SB0()   __builtin_amdgcn_sched_barrier(0)

#define GL16(dst, ptr, off) \
    asm volatile("global_load_dwordx4 %0, %1, off offset:" #off \
                 : "=v"(dst) : "v"(ptr))

#define MFMA(av, bv, c) __builtin_amdgcn_mfma_f32_16x16x32_f16(av, bv, c, 0, 0, 0)

// 16-MFMA cluster for m-group G (frags G*4..G*4+3) x bf0..bf3
#define MFMA16(G) do { \
    __builtin_amdgcn_s_setprio(1); \
    acc[(G)*4+0][0]=MFMA(af0,bf0,acc[(G)*4+0][0]); acc[(G)*4+0][1]=MFMA(af0,bf1,acc[(G)*4+0][1]); \
    acc[(G)*4+0][2]=MFMA(af0,bf2,acc[(G)*4+0][2]); acc[(G)*4+0][3]=MFMA(af0,bf3,acc[(G)*4+0][3]); \
    acc[(G)*4+1][0]=MFMA(af1,bf0,acc[(G)*4+1][0]); acc[(G)*4+1][1]=MFMA(af1,bf1,acc[(G)*4+1][1]); \
    acc[(G)*4+1][2]=MFMA(af1,bf2,acc[(G)*4+1][2]); acc[(G)*4+1][3]=MFMA(af1,bf3,acc[(G)*4+1][3]); \
    acc[(G)*4+2][0]=MFMA(af2,bf0,acc[(G)*4+2][0]); acc[(G)*4+2][1]=MFMA(af2,bf1,acc[(G)*4+2][1]); \
    acc[(G)*4+2][2]=MFMA(af2,bf2,acc[(G)*4+2][2]); acc[(G)*4+2][3]=MFMA(af2,bf3,acc[(G)*4+2][3]); \
    acc[(G)*4+3][0]=MFMA(af3,bf0,acc[(G)*4+3][0]); acc[(G)*4+3][1]=MFMA(af3,bf1,acc[(G)*4+3][1]); \
    acc[(G)*4+3][2]=MFMA(af3,bf2,acc[(G)*4+3][2]); acc[(G)*4+3][3]=MFMA(af3,bf3,acc[(G)*4+3][3]); \
    __builtin_amdgcn_s_setprio(0); \
    __builtin_amdgcn_sched_barrier(0); \
} while (0)

// issue A f32 loads for K-tile U, K-half KH: rows (ar, ar+128) x 32B -> 4 GL16
// blade = U>>2 (x-row offset (U>>2)*4194304 elems); channel = (U&3)*64+KH*32
#define ISSUE_A(U, KH, R) do { \
    const float* _p = pA + (size_t)((U) >> 2) * 4194304 + ((U) & 3) * 64 + (KH) * 32; \
    GL16(R##0, _p, 0); GL16(R##1, _p, 16); \
    const float* _q = _p + 32768; \
    GL16(R##2, _q, 0); GL16(R##3, _q, 16); \
} while (0)

// cvt 16 f32 -> 2 swizzled ds_write_b128 into A region at f16-offset OFF
#define WRITE_A(OFF, R) do { \
    f16x8 h0, h1; \
    h0[0]=(_Float16)R##0[0]; h0[1]=(_Float16)R##0[1]; h0[2]=(_Float16)R##0[2]; h0[3]=(_Float16)R##0[3]; \
    h0[4]=(_Float16)R##1[0]; h0[5]=(_Float16)R##1[1]; h0[6]=(_Float16)R##1[2]; h0[7]=(_Float16)R##1[3]; \
    h1[0]=(_Float16)R##2[0]; h1[1]=(_Float16)R##2[1]; h1[2]=(_Float16)R##2[2]; h1[3]=(_Float16)R##2[3]; \
    h1[4]=(_Float16)R##3[0]; h1[5]=(_Float16)R##3[1]; h1[6]=(_Float16)R##3[2]; h1[7]=(_Float16)R##3[3]; \
    _Float16* _wp = lds + (OFF) + aw0; \
    *(f16x8*)(_wp) = h0; \
    *(f16x8*)(_wp + 4096) = h1; \
} while (0)

// stage B K-tile U, K-half KH into dbuf at f16-offset TB (2 gload_lds)
#define STAGE_B(U, KH, TB) do { \
    const _Float16* _s = gBs + (U) * 64 + (KH) * 32; \
    _Float16* _d = lds + (TB) + 16384 + (KH) * 8192 + tid * 8; \
    async16(_s, _d); \
    async16(_s + 131072, _d + 4096); \
} while (0)

// read 4 A frags (m-group G) from A region at f16-offset BASE
#define LDA4(G, BASE) do { \
    const _Float16* _a = lds + (BASE) + aoff + (G) * 2048; \
    af0 = *(const f16x8*)(_a);        af1 = *(const f16x8*)(_a + 512); \
    af2 = *(const f16x8*)(_a + 1024); af3 = *(const f16x8*)(_a + 1536); \
} while (0)

// read 4 B frags from B region at f16-offset BASE
#define LDB4(BASE) do { \
    const _Float16* _b = lds + (BASE) + boff; \
    bf0 = *(const f16x8*)(_b);        bf1 = *(const f16x8*)(_b + 512); \
    bf2 = *(const f16x8*)(_b + 1024); bf3 = *(const f16x8*)(_b + 1536); \
} while (0)

__global__ __launch_bounds__(512, 2) void ga_gemm(const float* __restrict__ A,    // x f32
                                                  const _Float16* __restrict__ Bt,// WcatT
                                                  const float*  __restrict__ bias,
                                                  float* __restrict__ out) {
    __shared__ _Float16 lds[2 * 32768] __attribute__((aligned(16)));  // 128 KiB

    const int tid  = threadIdx.x;
    const int lane = tid & 63;
    const int wid  = tid >> 6;
    const int wm   = wid >> 2;          // 0..1  (M half of 256)
    const int wn   = wid & 3;           // 0..3  (N quarter of 256)
    const int l15  = lane & 15;
    const int lg   = lane >> 4;

    // XCD-aware bijective swizzle: 256 blocks, 8 XCDs, 32 contiguous each
    const int bid = blockIdx.x;
    const int swz = (bid & 7) * 32 + (bid >> 3);
    const int mt  = swz >> 2, nt = swz & 3;
    const int m0  = mt * 256,  n0 = nt * 256;

    // A reg-staging: 4 threads/row; slots rows (ar, ar+128), 32B f32 chunk ac
    const int ar = tid >> 2, ac = tid & 3;
    const float* pA = A + (size_t)(m0 + ar) * 256 + ac * 8;
    const int aw0 = ar * 32 + (ac ^ ((ar >> 1) & 3)) * 8;   // f16 units (+4096 row+128)

    // B staging (slot s -> row s>>2, chunk s&3; source chunk pre-swizzled)
    const int r0 = tid >> 2;
    const int g0 = (tid & 3) ^ ((r0 >> 1) & 3);
    const _Float16* gBs = Bt + (size_t)(n0 + r0) * 1024 + g0 * 8;
    // rows +128 at gBs + 131072 (same swizzle phase)

    // fragment ds_read offsets (f16 units); phys chunk = lg ^ ((row>>1)&3)
    const int sc   = lg ^ ((l15 >> 1) & 3);
    const int aoff = (wm * 128 + l15) * 32 + sc * 8;
    const int boff = (wn * 64  + l15) * 32 + sc * 8;

    f32x4 acc[8][4] = {};
    f32x4 u0, u1, u2, u3, v0, v1, v2, v3;
    f16x8 af0, af1, af2, af3, bf0, bf1, bf2, bf3;

    // prologue: tile 0 -> buf0; queue [Ak0:4, Bkh0:2, Ak1:4, Bkh1:2]
    ISSUE_A(0, 0, u);
    STAGE_B(0, 0, 0);
    ISSUE_A(0, 1, v);
    STAGE_B(0, 1, 0);
    VMW(6);  SB0();                 // drains A-k0(0), B-kh0(0)
    WRITE_A(0, u);                  // A-kh0(0) -> buf0
    LGKM0();
    BARRIER();
    // invariant entering tile 0: [A-k1(0) in v:4, B-kh1(0):2]

#pragma unroll 1
    for (int t = 0; t < 15; ++t) {
        const int db = (t & 1) << 15;
        const int tb = db ^ 32768;
        // ph1: reads kh0 G0 + B-kh0; issue A-k0(t+1). NO gate.
        LDA4(0, db);  LDB4(db + 16384);
        ISSUE_A(t + 1, 0, u);
        BARRIER();  LGKM0();  SB0();
        MFMA16(0);
        BARRIER();
        // ph2: reads kh0 G1; issue B-kh0(t+1); GATE; write A-kh1(t)
        LDA4(1, db);
        STAGE_B(t + 1, 0, tb);
        VMW(6);  SB0();             // drains A-k1(t) regs (v) + B-kh1(t) LDS
        WRITE_A(db + 8192, v);
        BARRIER();  LGKM0();  SB0();
        MFMA16(1);
        BARRIER();
        // ph3: reads kh1 G0 + B-kh1; issue A-k1(t+1). NO gate.
        LDA4(0, db + 8192);  LDB4(db + 24576);
        ISSUE_A(t + 1, 1, v);
        BARRIER();  LGKM0();  SB0();
        MFMA16(0);
        BARRIER();
        // ph4: reads kh1 G1; issue B-kh1(t+1); GATE; write A-kh0(t+1)
        LDA4(1, db + 8192);
        STAGE_B(t + 1, 1, tb);
        VMW(6);  SB0();             // drains A-k0(t+1) regs (u) + B-kh0(t+1) LDS
        WRITE_A(tb, u);
        BARRIER();  LGKM0();  SB0();
        MFMA16(1);
        BARRIER();
    }

    // tile 15 (db = 32768): no staging; single VMW(0) gate at ph2
    {
        const int db = 32768;
        LDA4(0, db);  LDB4(db + 16384);
        BARRIER();  LGKM0();  SB0();
        MFMA16(0);
        BARRIER();
        LDA4(1, db);
        VMW(0);  SB0();             // drains A-k1(15) regs (v) + B-kh1(15) LDS
        WRITE_A(db + 8192, v);
        BARRIER();  LGKM0();  SB0();
        MFMA16(1);
        BARRIER();
        LDA4(0, db + 8192);  LDB4(db + 24576);
        BARRIER();  LGKM0();  SB0();
        MFMA16(0);
        BARRIER();
        LDA4(1, db + 8192);
        LGKM0();  SB0();
        MFMA16(1);
    }

    // epilogue: C/D layout col=lane&15 (n), row=(lane>>4)*4+r (m)
    const size_t outBase = (size_t)nt * 16384 * 256;   // blade kb == nt
    const int ucol = wn * 64 + l15;
    float bv[4];
#pragma unroll
    for (int fn = 0; fn < 4; ++fn) bv[fn] = bias[nt * 256 + ucol + fn * 16];
#pragma unroll
    for (int fm = 0; fm < 8; ++fm) {
        const int m = m0 + wm * 128 + fm * 16 + lg * 4;
#pragma unroll
        for (int r = 0; r < 4; ++r) {
            float* op = out + outBase + (size_t)(m + r) * 256;
#pragma unroll
            for (int fn = 0; fn < 4; ++fn)
                op[ucol + fn * 16] = acc[fm][fn][r] + bv[fn];
        }
    }
}

// ---------------------------------------------------------------------------
extern "C" void kernel_launch(void* const* d_in, const int* in_sizes, int n_in,
                              void* d_out, int out_size, void* d_ws, size_t ws_size,
                              hipStream_t stream) {
    (void)in_sizes; (void)n_in; (void)out_size; (void)ws_size;
    const float* x = (const float*)d_in[0];   // (65536, 256)
    const float* W = (const float*)d_in[1];   // (256, 1024)
    const float* b = (const float*)d_in[2];   // (1024,)
    float* out = (float*)d_out;               // (65536, 256)

    _Float16* Wt = (_Float16*)d_ws;           // 2 MB

    build_wcatT<<<4096, 256, 0, stream>>>(W, Wt);
    ga_gemm<<<256, 512, 0, stream>>>(x, Wt, b, out);
}